// Round 2
// baseline (515.773 us; speedup 1.0000x reference)
//
#include <hip/hip_runtime.h>
#include <math.h>

typedef __attribute__((ext_vector_type(8))) short short8;
typedef __attribute__((ext_vector_type(4))) float floatx4;

__device__ inline float bf2f(short s) {
    union { unsigned u; float f; } x; x.u = ((unsigned)(unsigned short)s) << 16; return x.f;
}
__device__ inline short f2bf(float f) {
    union { float f; unsigned u; } x; x.f = f;
    unsigned r = x.u + 0x7fff + ((x.u >> 16) & 1);
    return (short)(r >> 16);
}

struct WSet {
    const float *fw1, *fb1, *fw2, *sw1, *sb1, *sw2, *sb2, *dw1, *db1, *dw2, *db2;
};

// ---------------- weight prep (both scales, blockIdx.y = scale) ----------------
// W1f: [c 0..4][kc 0..11][g 0..15][lane][8]; m=c*256+g*16+(l&15) (0-pad >=1152), k=kc*32+(l>>4)*8+e
// W2af: [ka 0..15][g 0..7][lane][8] from fw2 [128x512]
// W2bf: [kb 0..23][g 0..7][lane][8]; r=g*16+(l&15): sw2 (r<64,krel<512) / dw2 (r==64,512<=krel<640) / 0
// B1p: 1280 (0-pad), B2bp: 128 (0-pad)
__global__ __launch_bounds__(256) void wprep(WSet a0, WSet a1,
    short* __restrict__ W1f, short* __restrict__ W2af, short* __restrict__ W2bf,
    float* __restrict__ B1p, float* __restrict__ B2bp)
{
    const int s = blockIdx.y;
    const WSet A = s ? a1 : a0;
    W1f  += (size_t)s * 491520;
    W2af += (size_t)s * 65536;
    W2bf += (size_t)s * 98304;
    B1p  += s * 1280;
    B2bp += s * 128;
    int id = blockIdx.x * 256 + threadIdx.x;
    if (id < 491520) {
        int e = id & 7, l = (id >> 3) & 63, g = (id >> 9) & 15, rest = id >> 13;
        int kc = rest % 12, c = rest / 12;
        int m = c * 256 + g * 16 + (l & 15);
        int k = kc * 32 + (l >> 4) * 8 + e;
        float v = 0.f;
        if (m < 512) v = A.fw1[m * 384 + k];
        else if (m < 1024) v = A.sw1[(m - 512) * 384 + k];
        else if (m < 1152) v = A.dw1[(m - 1024) * 384 + k];
        W1f[id] = f2bf(v);
        return;
    }
    id -= 491520;
    if (id < 65536) {
        int e = id & 7, l = (id >> 3) & 63, g = (id >> 9) & 7, ka = id >> 12;
        int r = g * 16 + (l & 15), k = ka * 32 + (l >> 4) * 8 + e;
        W2af[id] = f2bf(A.fw2[r * 512 + k]);
        return;
    }
    id -= 65536;
    if (id < 98304) {
        int e = id & 7, l = (id >> 3) & 63, g = (id >> 9) & 7, kb = id >> 12;
        int r = g * 16 + (l & 15), krel = kb * 32 + (l >> 4) * 8 + e;
        float v = 0.f;
        if (r < 64 && krel < 512) v = A.sw2[r * 512 + krel];
        else if (r == 64 && krel >= 512 && krel < 640) v = A.dw2[krel - 512];
        W2bf[id] = f2bf(v);
        return;
    }
    id -= 98304;
    if (id < 1280) {
        float v = 0.f;
        if (id < 512) v = A.fb1[id];
        else if (id < 1024) v = A.sb1[id - 512];
        else if (id < 1152) v = A.db1[id - 1024];
        B1p[id] = v;
        return;
    }
    id -= 1280;
    if (id < 128) B2bp[id] = id < 64 ? A.sb2[id] : id == 64 ? A.db2[0] : 0.f;
}

// ---------------- xprep ----------------
__global__ __launch_bounds__(256) void xprep(const float* __restrict__ x,
                                             short* __restrict__ xT, short* __restrict__ x1T)
{
    __shared__ float xt[64 * 129];
    const int ip = blockIdx.x;
    const int cg = blockIdx.y;
    const int b  = blockIdx.z;
    const int t  = threadIdx.x;
    #pragma unroll
    for (int u = 0; u < 32; u++) {
        int idx = t + 256 * u;
        int c = idx >> 7, sp = idx & 127;
        xt[c * 129 + sp] = x[(((long)b * 384 + cg * 64 + c) * 64 + ip * 2 + (sp >> 6)) * 64 + (sp & 63)];
    }
    __syncthreads();
    {
        int sp = t >> 1, ch = t & 1;
        short tmp[32];
        #pragma unroll
        for (int cc = 0; cc < 32; cc++) tmp[cc] = f2bf(xt[(ch * 32 + cc) * 129 + sp]);
        short* dst = xT + ((long)b * 4096 + ip * 128 + sp) * 384 + cg * 64 + ch * 32;
        #pragma unroll
        for (int v = 0; v < 4; v++) *(short8*)(dst + v * 8) = *(short8*)(tmp + v * 8);
    }
    {
        int j1 = t >> 3, c8 = t & 7;
        short tmp[8];
        #pragma unroll
        for (int e = 0; e < 8; e++) {
            int c = c8 * 8 + e;
            float v = 0.25f * (xt[c * 129 + j1 * 2]      + xt[c * 129 + j1 * 2 + 1] +
                               xt[c * 129 + 64 + j1 * 2] + xt[c * 129 + 64 + j1 * 2 + 1]);
            tmp[e] = f2bf(v);
        }
        *(short8*)(x1T + ((long)b * 1024 + ip * 32 + j1) * 384 + cg * 64 + c8 * 8) = *(short8*)tmp;
    }
}

// ---------------- fused MLP v5: n-tile 32 for occupancy ----------------
// Counters showed latency-bound (all pipes <25%, occupancy 18.8% at 2 blocks/CU).
// n=32: acc footprint halves (acc1 8xfx4 + acc2 8xfx4), LDS 80->40 KB (xs 24 + hs 16)
// -> 3 blocks/CU (launch_bounds cap ~170 VGPR). W1/W2 L2 traffic doubles but stays
// under the 34.5 TB/s L2 ceiling.
__global__ __launch_bounds__(256, 3) void fused_mlp(
    const short* __restrict__ W1f_, const float* __restrict__ B1p_,
    const short* __restrict__ W2af_, const float* __restrict__ fb2_0, const float* __restrict__ fb2_1,
    const short* __restrict__ W2bf_, const float* __restrict__ B2bp_,
    const short* __restrict__ xT, const short* __restrict__ x1T,
    float* __restrict__ feat0, float* __restrict__ feat1,
    short* __restrict__ Eg0, short* __restrict__ Eg1,
    float* __restrict__ pu0, float* __restrict__ pu1)
{
    __shared__ short xs[12 * 1024];   // 24 KB
    __shared__ short hs[8 * 1024];    // 16 KB (256 k-rows x 32 n, B-fragment order)
    const int tid = threadIdx.x;
    const int wid = tid >> 6, lane = tid & 63;
    const int l15 = lane & 15, q = lane >> 4;
    const int bx = blockIdx.x, b = blockIdx.y;
    const int sc = bx >= 128;
    const int tile = sc ? bx - 128 : bx;
    const int N = sc ? 1024 : 4096;
    const int n0 = tile * 32;
    const short* XT = sc ? x1T : xT;
    const short* W1f = W1f_ + (size_t)sc * 491520;
    const float* B1p = B1p_ + sc * 1280;
    const short* W2af = W2af_ + (size_t)sc * 65536;
    const short* W2bf = W2bf_ + (size_t)sc * 98304;
    const float* fb2 = sc ? fb2_1 : fb2_0;
    const float* B2bp = B2bp_ + sc * 128;
    float* feat = (sc ? feat1 : feat0) + (long)b * 128 * N;
    short* Eg = (sc ? Eg1 : Eg0) + (long)b * 65 * N;
    float* pu = sc ? pu1 : pu0;
    const int npart = sc ? 32 : 128;

    // stage x tile [32 n x 384 k] into fragment-order LDS
    {
        const int n = tid >> 3;          // 0..31
        const int c0 = (tid & 7) * 6;    // 8 threads cover 48 c-groups
        const short* src = XT + ((long)b * N + n0 + n) * 384 + c0 * 8;
        const int jj = n >> 4, nl = n & 15;
        #pragma unroll
        for (int i = 0; i < 6; i++) {
            int c = c0 + i;
            int kc = c >> 2, qq = c & 3;
            *(short8*)(xs + kc * 1024 + jj * 512 + ((qq << 4) | nl) * 8) =
                *(const short8*)(src + i * 8);
        }
    }
    __syncthreads();

    floatx4 acc2[4][2];
    #pragma unroll
    for (int i = 0; i < 4; i++)
        #pragma unroll
        for (int j = 0; j < 2; j++) acc2[i][j] = floatx4{0.f, 0.f, 0.f, 0.f};

    auto phase2 = [&](int pc) {
        if (pc < 2) {
            const short* WA = W2af + (size_t)pc * 32768;
            short8 hb[2][2], wa0[2], wa1[2];
            #pragma unroll
            for (int j = 0; j < 2; j++) hb[0][j] = *(short8*)(hs + j * 512 + lane * 8);
            wa0[0] = *(const short8*)(WA + (2 * wid) * 512 + lane * 8);
            wa1[0] = *(const short8*)(WA + (2 * wid + 1) * 512 + lane * 8);
            #pragma unroll
            for (int kc2 = 0; kc2 < 8; kc2++) {
                short8 bfr[2];
                #pragma unroll
                for (int j = 0; j < 2; j++) bfr[j] = hb[kc2 & 1][j];
                short8 aA = wa0[kc2 & 1], aB = wa1[kc2 & 1];
                if (kc2 + 1 < 8) {
                    #pragma unroll
                    for (int j = 0; j < 2; j++)
                        hb[(kc2 + 1) & 1][j] = *(short8*)(hs + (kc2 + 1) * 1024 + j * 512 + lane * 8);
                    wa0[(kc2 + 1) & 1] = *(const short8*)(WA + ((kc2 + 1) * 8 + 2 * wid) * 512 + lane * 8);
                    wa1[(kc2 + 1) & 1] = *(const short8*)(WA + ((kc2 + 1) * 8 + 2 * wid + 1) * 512 + lane * 8);
                }
                #pragma unroll
                for (int j = 0; j < 2; j++) {
                    acc2[0][j] = __builtin_amdgcn_mfma_f32_16x16x32_bf16(aA, bfr[j], acc2[0][j], 0, 0, 0);
                    acc2[1][j] = __builtin_amdgcn_mfma_f32_16x16x32_bf16(aB, bfr[j], acc2[1][j], 0, 0, 0);
                }
            }
        } else {
            const short* WB = W2bf + (size_t)(pc - 2) * 32768;
            short8 hb[2][2], wc[2], wd[2];
            #pragma unroll
            for (int j = 0; j < 2; j++) hb[0][j] = *(short8*)(hs + j * 512 + lane * 8);
            wc[0] = *(const short8*)(WB + wid * 512 + lane * 8);
            wd[0] = *(const short8*)(WB + 4 * 512 + lane * 8);
            #pragma unroll
            for (int kc2 = 0; kc2 < 8; kc2++) {
                short8 bfr[2];
                #pragma unroll
                for (int j = 0; j < 2; j++) bfr[j] = hb[kc2 & 1][j];
                short8 aC = wc[kc2 & 1], aD = wd[kc2 & 1];
                if (kc2 + 1 < 8) {
                    #pragma unroll
                    for (int j = 0; j < 2; j++)
                        hb[(kc2 + 1) & 1][j] = *(short8*)(hs + (kc2 + 1) * 1024 + j * 512 + lane * 8);
                    wc[(kc2 + 1) & 1] = *(const short8*)(WB + ((kc2 + 1) * 8 + wid) * 512 + lane * 8);
                    wd[(kc2 + 1) & 1] = *(const short8*)(WB + ((kc2 + 1) * 8 + 4) * 512 + lane * 8);
                }
                #pragma unroll
                for (int j = 0; j < 2; j++)
                    acc2[2][j] = __builtin_amdgcn_mfma_f32_16x16x32_bf16(aC, bfr[j], acc2[2][j], 0, 0, 0);
                if (wid == 0) {
                    #pragma unroll
                    for (int j = 0; j < 2; j++)
                        acc2[3][j] = __builtin_amdgcn_mfma_f32_16x16x32_bf16(aD, bfr[j], acc2[3][j], 0, 0, 0);
                }
            }
        }
    };

    for (int c = 0; c < 5; c++) {
        // phase1: h rows c*256 + wid*64 .. +63
        // 2-deep A (global) / 1-deep B (LDS) software pipeline
        floatx4 acc1[4][2];
        #pragma unroll
        for (int i = 0; i < 4; i++)
            #pragma unroll
            for (int j = 0; j < 2; j++) acc1[i][j] = floatx4{0.f, 0.f, 0.f, 0.f};
        const short* Wb = W1f + (long)c * 98304;
        short8 abuf[2][4], bbuf[2][2];
        #pragma unroll
        for (int i = 0; i < 4; i++) {
            abuf[0][i] = *(const short8*)(Wb + (wid * 4 + i) * 512 + lane * 8);
            abuf[1][i] = *(const short8*)(Wb + (16 + wid * 4 + i) * 512 + lane * 8);
        }
        #pragma unroll
        for (int j = 0; j < 2; j++) bbuf[0][j] = *(short8*)(xs + j * 512 + lane * 8);
        #pragma unroll
        for (int kc = 0; kc < 12; kc++) {
            short8 ac[4], bc[2];
            #pragma unroll
            for (int i = 0; i < 4; i++) ac[i] = abuf[kc & 1][i];
            #pragma unroll
            for (int j = 0; j < 2; j++) bc[j] = bbuf[kc & 1][j];
            if (kc + 2 < 12) {
                #pragma unroll
                for (int i = 0; i < 4; i++)
                    abuf[kc & 1][i] = *(const short8*)(Wb + ((kc + 2) * 16 + wid * 4 + i) * 512 + lane * 8);
            }
            if (kc + 1 < 12) {
                #pragma unroll
                for (int j = 0; j < 2; j++)
                    bbuf[(kc + 1) & 1][j] = *(short8*)(xs + (kc + 1) * 1024 + j * 512 + lane * 8);
            }
            #pragma unroll
            for (int i = 0; i < 4; i++)
                #pragma unroll
                for (int j = 0; j < 2; j++)
                    acc1[i][j] = __builtin_amdgcn_mfma_f32_16x16x32_bf16(ac[i], bc[j], acc1[i][j], 0, 0, 0);
        }
        if (c > 0) phase2(c - 1);
        __syncthreads();   // hs readers done
        // h-chunk -> hs (bias + relu + bf16), phase-2 B-fragment order
        #pragma unroll
        for (int i = 0; i < 4; i++) {
            const int kc2 = wid * 2 + (i >> 1);
            const int qf = (i & 1) * 2 + (q >> 1);
            const int e0 = 4 * (q & 1);
            const int mrow = c * 256 + wid * 64 + i * 16 + q * 4;
            float bw[4];
            #pragma unroll
            for (int rr = 0; rr < 4; rr++) bw[rr] = B1p[mrow + rr];
            #pragma unroll
            for (int j = 0; j < 2; j++) {
                short pk[4];
                #pragma unroll
                for (int rr = 0; rr < 4; rr++)
                    pk[rr] = f2bf(fmaxf(acc1[i][j][rr] + bw[rr], 0.f));
                *(unsigned long long*)(hs + kc2 * 1024 + j * 512 + ((qf << 4) | l15) * 8 + e0) =
                    *(unsigned long long*)pk;
            }
        }
        __syncthreads();   // hs visible
    }
    phase2(4);

    // epilogue: feat (slots 0,1)
    #pragma unroll
    for (int slot = 0; slot < 2; slot++) {
        int row0 = (2 * wid + slot) * 16 + q * 4;
        #pragma unroll
        for (int rr = 0; rr < 4; rr++) {
            float bv = fb2[row0 + rr];
            #pragma unroll
            for (int j = 0; j < 2; j++)
                feat[(long)(row0 + rr) * N + n0 + 16 * j + l15] = acc2[slot][j][rr] + bv;
        }
    }
    __syncthreads();               // all phase2(4) hs reads done; reuse hs
    float* puld = (float*)hs;
    // E slot 2: rows wid*16 .. +15
    #pragma unroll
    for (int rr = 0; rr < 4; rr++) {
        int row = wid * 16 + q * 4 + rr;
        float bv = B2bp[row];
        float s = 0.f;
        #pragma unroll
        for (int j = 0; j < 2; j++) {
            float e = expf(acc2[2][j][rr] + bv);
            Eg[(long)row * N + n0 + 16 * j + l15] = f2bf(e);
            s += e;
        }
        s += __shfl_xor(s, 1); s += __shfl_xor(s, 2);
        s += __shfl_xor(s, 4); s += __shfl_xor(s, 8);
        if (l15 == 0) puld[row] = s;
    }
    // E slot 3 (wave 0): row 64 only
    if (wid == 0) {
        #pragma unroll
        for (int rr = 0; rr < 4; rr++) {
            int row = 64 + q * 4 + rr;
            bool valid = (row == 64);
            float bv = B2bp[64];
            float s = 0.f;
            #pragma unroll
            for (int j = 0; j < 2; j++) {
                float e = expf(acc2[3][j][rr] + bv);
                if (valid) {
                    Eg[(long)64 * N + n0 + 16 * j + l15] = f2bf(e);
                    s += e;
                }
            }
            s += __shfl_xor(s, 1); s += __shfl_xor(s, 2);
            s += __shfl_xor(s, 4); s += __shfl_xor(s, 8);
            if (valid && l15 == 0) puld[64] = s;
        }
    }
    __syncthreads();
    if (tid < 65)
        pu[((long)b * npart + tile) * 65 + tid] = puld[tid];
}

// ---------------- sk_step (both scales): eu from pin; v-step; next u-partials ----------------
__global__ __launch_bounds__(256) void sk_step(
    const short* __restrict__ Eg0, const short* __restrict__ Eg1,
    const float* __restrict__ pin0, const float* __restrict__ pin1,
    float* __restrict__ pout0, float* __restrict__ pout1, int nin0, int nin1)
{
    __shared__ short Es[65 * 264];
    __shared__ float evs[256];
    __shared__ float eus[65];
    const int t = threadIdx.x;
    const int bx = blockIdx.x, b = blockIdx.y;
    const int sc = bx >= 16;
    const int chunk = sc ? bx - 16 : bx;
    const int N = sc ? 1024 : 4096;
    const float invN = sc ? (1.0f / 1024.0f) : (1.0f / 4096.0f);
    const int n0 = chunk * 256;
    const short* Eb = (sc ? Eg1 : Eg0) + (long)b * 65 * N;
    const float* pin = sc ? pin1 : pin0;
    const int nin = sc ? nin1 : nin0;
    float* pout = sc ? pout1 : pout0;
    const int nout = sc ? 4 : 16;
    if (t < 65) {
        float s = 0.f;
        for (int ch = 0; ch < nin; ch++) s += pin[((long)b * nin + ch) * 65 + t];
        eus[t] = (1.0f / 65.0f) / s;
    }
    for (int it = t; it < 2080; it += 256) {
        int k = it >> 5, n8 = it & 31;
        *(short8*)(Es + k * 264 + n8 * 8) = *(const short8*)(Eb + (long)k * N + n0 + n8 * 8);
    }
    __syncthreads();
    float sv = 0.f;
    #pragma unroll 4
    for (int k = 0; k < 65; k++) sv += bf2f(Es[k * 264 + t]) * eus[k];
    evs[t] = invN / sv;
    __syncthreads();
    const int wid = t >> 6, lane = t & 63;
    for (int k = wid; k < 65; k += 4) {
        const short* er = Es + k * 264 + lane * 4;
        float4 v4 = *(const float4*)&evs[lane * 4];
        float s = bf2f(er[0]) * v4.x + bf2f(er[1]) * v4.y + bf2f(er[2]) * v4.z + bf2f(er[3]) * v4.w;
        #pragma unroll
        for (int off = 32; off >= 1; off >>= 1) s += __shfl_xor(s, off);
        if (lane == 0) pout[((long)b * nout + chunk) * 65 + k] = s;
    }
}

// ---------------- sk_desc (both scales): eu; final v-step; P; desc partials via MFMA ----------------
__global__ __launch_bounds__(256) void sk_desc(
    const short* __restrict__ Eg0, const short* __restrict__ Eg1,
    const float* __restrict__ pin0, const float* __restrict__ pin1,
    const float* __restrict__ feat0, const float* __restrict__ feat1,
    float* __restrict__ part0, float* __restrict__ part1, int nin0, int nin1)
{
    __shared__ short Es[65 * 264];
    __shared__ float eus[65];
    const int t = threadIdx.x;
    const int bx = blockIdx.x, b = blockIdx.y;
    const int sc = bx >= 16;
    const int chunk = sc ? bx - 16 : bx;
    const int N = sc ? 1024 : 4096;
    const float invN = sc ? (1.0f / 1024.0f) : (1.0f / 4096.0f);
    const int nch = sc ? 4 : 16;
    const int n0 = chunk * 256;
    const short* Eb = (sc ? Eg1 : Eg0) + (long)b * 65 * N;
    const float* pin = sc ? pin1 : pin0;
    const int nin = sc ? nin1 : nin0;
    const float* fb = (sc ? feat1 : feat0) + (long)b * 128 * N;
    float* part = sc ? part1 : part0;
    if (t < 65) {
        float s = 0.f;
        for (int ch = 0; ch < nin; ch++) s += pin[((long)b * nin + ch) * 65 + t];
        eus[t] = (1.0f / 65.0f) / s;
    }
    for (int it = t; it < 2080; it += 256) {
        int k = it >> 5, n8 = it & 31;
        *(short8*)(Es + k * 264 + n8 * 8) = *(const short8*)(Eb + (long)k * N + n0 + n8 * 8);
    }
    __syncthreads();
    float sv = 0.f;
    #pragma unroll 4
    for (int k = 0; k < 65; k++) sv += bf2f(Es[k * 264 + t]) * eus[k];
    float evt = invN / sv;
    #pragma unroll 4
    for (int k = 0; k < 64; k++)
        Es[k * 264 + t] = f2bf(bf2f(Es[k * 264 + t]) * eus[k] * evt);
    __syncthreads();
    const int wid = t >> 6, lane = t & 63;
    const int l15 = lane & 15, q = lane >> 4;
    float* pb = part + ((long)b * nch + chunk) * 8256;
    // P row-sum partials (denominator)
    for (int k = wid; k < 64; k += 4) {
        const short* er = Es + k * 264 + lane * 4;
        float s = bf2f(er[0]) + bf2f(er[1]) + bf2f(er[2]) + bf2f(er[3]);
        #pragma unroll
        for (int off = 32; off >= 1; off >>= 1) s += __shfl_xor(s, off);
        if (lane == 0) pb[8192 + k] = s;
    }
    // MFMA einsum: wave wid owns c rows wid*32 .. +31 (2 m-tiles), all 64 k-cols (4 n-tiles)
    floatx4 acc[2][4];
    #pragma unroll
    for (int mt = 0; mt < 2; mt++)
        #pragma unroll
        for (int nt = 0; nt < 4; nt++) acc[mt][nt] = floatx4{0.f, 0.f, 0.f, 0.f};
    #pragma unroll 2
    for (int ks = 0; ks < 8; ks++) {
        short8 ah[2], al[2];
        #pragma unroll
        for (int mt = 0; mt < 2; mt++) {
            const float* fp = fb + (long)(wid * 32 + mt * 16 + l15) * N + n0 + ks * 32 + q * 8;
            float4 v0 = *(const float4*)fp;
            float4 v1 = *(const float4*)(fp + 4);
            float va[8] = {v0.x, v0.y, v0.z, v0.w, v1.x, v1.y, v1.z, v1.w};
            short hh[8], ll[8];
            #pragma unroll
            for (int e = 0; e < 8; e++) {
                short h = f2bf(va[e]);
                hh[e] = h;
                ll[e] = f2bf(va[e] - bf2f(h));
            }
            ah[mt] = *(short8*)hh;
            al[mt] = *(short8*)ll;
        }
        #pragma unroll
        for (int nt = 0; nt < 4; nt++) {
            short8 bfr = *(short8*)(Es + (nt * 16 + l15) * 264 + ks * 32 + q * 8);
            #pragma unroll
            for (int mt = 0; mt < 2; mt++) {
                acc[mt][nt] = __builtin_amdgcn_mfma_f32_16x16x32_bf16(al[mt], bfr, acc[mt][nt], 0, 0, 0);
                acc[mt][nt] = __builtin_amdgcn_mfma_f32_16x16x32_bf16(ah[mt], bfr, acc[mt][nt], 0, 0, 0);
            }
        }
    }
    // C/D layout: col = lane&15 (k-index), row = q*4+rr (c-row within tile)
    #pragma unroll
    for (int mt = 0; mt < 2; mt++)
        #pragma unroll
        for (int nt = 0; nt < 4; nt++)
            #pragma unroll
            for (int rr = 0; rr < 4; rr++)
                pb[(wid * 32 + mt * 16 + q * 4 + rr) * 64 + nt * 16 + l15] = acc[mt][nt][rr];
}

// ---------------- desc reduce (both scales; separate desc buffers) ----------------
__global__ __launch_bounds__(256) void desc_reduce(
    const float* __restrict__ part0, const float* __restrict__ part1,
    float* __restrict__ desc0, float* __restrict__ desc1, int b0)
{
    __shared__ float cred[4][8];
    const int bx = blockIdx.x, b = blockIdx.y;
    const int sc = bx >= 4;
    const int kg = (bx & 3) * 16;
    const int nch = sc ? 4 : 16;
    const float* pb = (sc ? part1 : part0) + (long)b * nch * 8256;
    float* desc = sc ? desc1 : desc0;
    const int t = threadIdx.x;
    const int c = t & 127, kh = t >> 7;
    float a[8], rs[8];
    #pragma unroll
    for (int j = 0; j < 8; j++) { a[j] = 0.f; rs[j] = 0.f; }
    for (int ch = 0; ch < nch; ch++) {
        const float* p = pb + (long)ch * 8256;
        #pragma unroll
        for (int j = 0; j < 8; j++) a[j] += p[c * 64 + kg + kh * 8 + j];
        #pragma unroll
        for (int j = 0; j < 8; j++) rs[j] += p[8192 + kg + kh * 8 + j];
    }
    float sq[8];
    #pragma unroll
    for (int j = 0; j < 8; j++) {
        a[j] *= 1.0f / (rs[j] + 1e-8f);
        sq[j] = a[j] * a[j];
    }
    #pragma unroll
    for (int off = 32; off >= 1; off >>= 1)
        #pragma unroll
        for (int j = 0; j < 8; j++) sq[j] += __shfl_xor(sq[j], off);
    if ((t & 63) == 0) {
        #pragma unroll
        for (int j = 0; j < 8; j++) cred[t >> 6][j] = sq[j];
    }
    __syncthreads();
    float* d = desc + (long)(b0 + b) * 8192;
    #pragma unroll
    for (int j = 0; j < 8; j++) {
        float tot = cred[kh * 2][j] + cred[kh * 2 + 1][j];
        float inv = 1.0f / fmaxf(sqrtf(tot), 1e-12f);
        d[c * 64 + kg + kh * 8 + j] = a[j] * inv;
    }
}

// ---------------- final: g = mean(desc0,desc1); normalize ----------------
__global__ __launch_bounds__(256) void final_kernel(const float* __restrict__ desc0,
                                                    const float* __restrict__ desc1,
                                                    float* __restrict__ out)
{
    __shared__ float red[4];
    const int b = blockIdx.x;
    const float* d0 = desc0 + (long)b * 8192;
    const float* d1 = desc1 + (long)b * 8192;
    float s = 0;
    for (int i = threadIdx.x; i < 8192; i += 256) {
        float t = (d0[i] + d1[i]) * 0.5f; s += t * t;
    }
    const int wave = threadIdx.x >> 6, lane = threadIdx.x & 63;
    #pragma unroll
    for (int off = 32; off >= 1; off >>= 1) s += __shfl_xor(s, off);
    if (lane == 0) red[wave] = s;
    __syncthreads();
    float tot = red[0] + red[1] + red[2] + red[3];
    float inv = 1.0f / fmaxf(sqrtf(tot), 1e-12f);
    for (int i = threadIdx.x; i < 8192; i += 256)
        out[(long)b * 8192 + i] = (d0[i] + d1[i]) * 0.5f * inv;
}

extern "C" void kernel_launch(void* const* d_in, const int* in_sizes, int n_in,
                              void* d_out, int out_size, void* d_ws, size_t ws_size,
                              hipStream_t stream)
{
    (void)in_sizes; (void)n_in; (void)out_size;
    const float* x = (const float*)d_in[0];
    WSet ws2[2];
    const float* fb2p[2];
    for (int s = 0; s < 2; s++) {
        int o = 1 + s * 12;
        ws2[s].fw1 = (const float*)d_in[o + 0];  ws2[s].fb1 = (const float*)d_in[o + 1];
        ws2[s].fw2 = (const float*)d_in[o + 2];  fb2p[s]    = (const float*)d_in[o + 3];
        ws2[s].sw1 = (const float*)d_in[o + 4];  ws2[s].sb1 = (const float*)d_in[o + 5];
        ws2[s].sw2 = (const float*)d_in[o + 6];  ws2[s].sb2 = (const float*)d_in[o + 7];
        ws2[s].dw1 = (const float*)d_in[o + 8];  ws2[s].db1 = (const float*)d_in[o + 9];
        ws2[s].dw2 = (const float*)d_in[o + 10]; ws2[s].db2 = (const float*)d_in[o + 11];
    }

    const size_t fixed = ((size_t)2*491520*2 + 2*65536*2 + 2*98304*2
                        + 2*1280*4 + 2*128*4 + (size_t)2*16*8192*4) + (1 << 16);
    const size_t perb = (size_t)4096*384*2 + (size_t)1024*384*2
                      + (size_t)128*4096*4 + (size_t)128*1024*4
                      + (size_t)65*4096*2 + (size_t)65*1024*2
                      + (size_t)(128+32)*65*4 + (size_t)(16+4)*65*4
                      + (size_t)16*8256*4 + (size_t)4*8256*4 + 8192;
    int CB = 4;
    const int cand[3] = {16, 8, 4};
    for (int ci = 0; ci < 3; ci++)
        if (fixed + (size_t)cand[ci] * perb <= ws_size) { CB = cand[ci]; break; }

    char* p = (char*)d_ws;
    auto alloc = [&](size_t bytes) -> char* {
        char* r = p; p += (bytes + 255) & ~(size_t)255; return r;
    };
    short* W1f   = (short*)alloc((size_t)2 * 491520 * 2);
    short* W2af  = (short*)alloc((size_t)2 * 65536 * 2);
    short* W2bf  = (short*)alloc((size_t)2 * 98304 * 2);
    float* B1p   = (float*)alloc((size_t)2 * 1280 * 4);
    float* B2bp  = (float*)alloc((size_t)2 * 128 * 4);
    float* desc0 = (float*)alloc((size_t)16 * 8192 * 4);
    float* desc1 = (float*)alloc((size_t)16 * 8192 * 4);
    short* xT    = (short*)alloc((size_t)CB * 4096 * 384 * 2);
    short* x1T   = (short*)alloc((size_t)CB * 1024 * 384 * 2);
    float* feat0 = (float*)alloc((size_t)CB * 128 * 4096 * 4);
    float* feat1 = (float*)alloc((size_t)CB * 128 * 1024 * 4);
    short* Eg0   = (short*)alloc((size_t)CB * 65 * 4096 * 2);
    short* Eg1   = (short*)alloc((size_t)CB * 65 * 1024 * 2);
    float* puA0  = (float*)alloc((size_t)CB * 128 * 65 * 4);
    float* puA1  = (float*)alloc((size_t)CB * 32 * 65 * 4);
    float* puB0  = (float*)alloc((size_t)CB * 16 * 65 * 4);
    float* puB1  = (float*)alloc((size_t)CB * 4 * 65 * 4);
    float* part0 = (float*)alloc((size_t)CB * 16 * 8256 * 4);
    float* part1 = (float*)alloc((size_t)CB * 4 * 8256 * 4);

    wprep<<<dim3(2566, 2), 256, 0, stream>>>(ws2[0], ws2[1], W1f, W2af, W2bf, B1p, B2bp);

    for (int b0 = 0; b0 < 16; b0 += CB) {
        xprep<<<dim3(32, 6, CB), 256, 0, stream>>>(x + (size_t)b0 * 384 * 4096, xT, x1T);
        fused_mlp<<<dim3(160, CB), 256, 0, stream>>>(
            W1f, B1p, W2af, fb2p[0], fb2p[1], W2bf, B2bp,
            xT, x1T, feat0, feat1, Eg0, Eg1, puA0, puA1);
        sk_step<<<dim3(20, CB), 256, 0, stream>>>(Eg0, Eg1, puA0, puA1, puB0, puB1, 128, 32);
        sk_step<<<dim3(20, CB), 256, 0, stream>>>(Eg0, Eg1, puB0, puB1, puA0, puA1, 16, 4);
        sk_desc<<<dim3(20, CB), 256, 0, stream>>>(Eg0, Eg1, puA0, puA1,
                                                  feat0, feat1, part0, part1, 16, 4);
        desc_reduce<<<dim3(8, CB), 256, 0, stream>>>(part0, part1, desc0, desc1, b0);
    }
    final_kernel<<<16, 256, 0, stream>>>(desc0, desc1, (float*)d_out);
}

// Round 3
// 395.126 us; speedup vs baseline: 1.3053x; 1.3053x over previous
//
#include <hip/hip_runtime.h>
#include <math.h>

typedef __attribute__((ext_vector_type(8))) short short8;
typedef __attribute__((ext_vector_type(4))) float floatx4;

__device__ inline float bf2f(short s) {
    union { unsigned u; float f; } x; x.u = ((unsigned)(unsigned short)s) << 16; return x.f;
}
__device__ inline short f2bf(float f) {
    union { float f; unsigned u; } x; x.f = f;
    unsigned r = x.u + 0x7fff + ((x.u >> 16) & 1);
    return (short)(r >> 16);
}

struct WSet {
    const float *fw1, *fb1, *fw2, *sw1, *sb1, *sw2, *sb2, *dw1, *db1, *dw2, *db2;
};

// ---------------- weight prep (both scales, blockIdx.y = scale) ----------------
// W1f: [c 0..4][kc 0..11][g 0..15][lane][8]; m=c*256+g*16+(l&15) (0-pad >=1152), k=kc*32+(l>>4)*8+e
// W2af: [ka 0..15][g 0..7][lane][8] from fw2 [128x512]
// W2bf: [kb 0..23][g 0..7][lane][8]; r=g*16+(l&15): sw2 (r<64,krel<512) / dw2 (r==64,512<=krel<640) / 0
// B1p: 1280 (0-pad), B2bp: 128 (0-pad)
__global__ __launch_bounds__(256) void wprep(WSet a0, WSet a1,
    short* __restrict__ W1f, short* __restrict__ W2af, short* __restrict__ W2bf,
    float* __restrict__ B1p, float* __restrict__ B2bp)
{
    const int s = blockIdx.y;
    const WSet A = s ? a1 : a0;
    W1f  += (size_t)s * 491520;
    W2af += (size_t)s * 65536;
    W2bf += (size_t)s * 98304;
    B1p  += s * 1280;
    B2bp += s * 128;
    int id = blockIdx.x * 256 + threadIdx.x;
    if (id < 491520) {
        int e = id & 7, l = (id >> 3) & 63, g = (id >> 9) & 15, rest = id >> 13;
        int kc = rest % 12, c = rest / 12;
        int m = c * 256 + g * 16 + (l & 15);
        int k = kc * 32 + (l >> 4) * 8 + e;
        float v = 0.f;
        if (m < 512) v = A.fw1[m * 384 + k];
        else if (m < 1024) v = A.sw1[(m - 512) * 384 + k];
        else if (m < 1152) v = A.dw1[(m - 1024) * 384 + k];
        W1f[id] = f2bf(v);
        return;
    }
    id -= 491520;
    if (id < 65536) {
        int e = id & 7, l = (id >> 3) & 63, g = (id >> 9) & 7, ka = id >> 12;
        int r = g * 16 + (l & 15), k = ka * 32 + (l >> 4) * 8 + e;
        W2af[id] = f2bf(A.fw2[r * 512 + k]);
        return;
    }
    id -= 65536;
    if (id < 98304) {
        int e = id & 7, l = (id >> 3) & 63, g = (id >> 9) & 7, kb = id >> 12;
        int r = g * 16 + (l & 15), krel = kb * 32 + (l >> 4) * 8 + e;
        float v = 0.f;
        if (r < 64 && krel < 512) v = A.sw2[r * 512 + krel];
        else if (r == 64 && krel >= 512 && krel < 640) v = A.dw2[krel - 512];
        W2bf[id] = f2bf(v);
        return;
    }
    id -= 98304;
    if (id < 1280) {
        float v = 0.f;
        if (id < 512) v = A.fb1[id];
        else if (id < 1024) v = A.sb1[id - 512];
        else if (id < 1152) v = A.db1[id - 1024];
        B1p[id] = v;
        return;
    }
    id -= 1280;
    if (id < 128) B2bp[id] = id < 64 ? A.sb2[id] : id == 64 ? A.db2[0] : 0.f;
}

// ---------------- xprep (float4 x loads) ----------------
__global__ __launch_bounds__(256) void xprep(const float* __restrict__ x,
                                             short* __restrict__ xT, short* __restrict__ x1T)
{
    __shared__ float xt[64 * 129];
    const int ip = blockIdx.x;
    const int cg = blockIdx.y;
    const int b  = blockIdx.z;
    const int t  = threadIdx.x;
    #pragma unroll
    for (int u = 0; u < 8; u++) {
        int idx = t + 256 * u;             // 0..2047 float4 slots
        int c = idx >> 5, spq = idx & 31;  // sp = spq*4
        float4 v = *(const float4*)&x[(((long)b * 384 + cg * 64 + c) * 64 + ip * 2 + (spq >> 4)) * 64 + (spq & 15) * 4];
        float* d = &xt[c * 129 + spq * 4];
        d[0] = v.x; d[1] = v.y; d[2] = v.z; d[3] = v.w;
    }
    __syncthreads();
    {
        int sp = t >> 1, ch = t & 1;
        short tmp[32];
        #pragma unroll
        for (int cc = 0; cc < 32; cc++) tmp[cc] = f2bf(xt[(ch * 32 + cc) * 129 + sp]);
        short* dst = xT + ((long)b * 4096 + ip * 128 + sp) * 384 + cg * 64 + ch * 32;
        #pragma unroll
        for (int v = 0; v < 4; v++) *(short8*)(dst + v * 8) = *(short8*)(tmp + v * 8);
    }
    {
        int j1 = t >> 3, c8 = t & 7;
        short tmp[8];
        #pragma unroll
        for (int e = 0; e < 8; e++) {
            int c = c8 * 8 + e;
            float v = 0.25f * (xt[c * 129 + j1 * 2]      + xt[c * 129 + j1 * 2 + 1] +
                               xt[c * 129 + 64 + j1 * 2] + xt[c * 129 + 64 + j1 * 2 + 1]);
            tmp[e] = f2bf(v);
        }
        *(short8*)(x1T + ((long)b * 1024 + ip * 32 + j1) * 384 + cg * 64 + c8 * 8) = *(short8*)tmp;
    }
}

// ---------------- fused MLP v6: n=64 tile, 512 threads / 8 waves ----------------
// Same tile & traffic as v4 (best measured) but 8 waves of 32 m-rows each:
// LDS 80 KB -> 2 blocks/CU as before, yet 4 waves/SIMD (was 2) to fill the
// per-iteration latency bubbles R2 identified. acc1 2x4, acc2 2x4 per wave;
// launch_bounds(512,4) caps VGPR at 128. phase2 runs BEFORE phase1 each chunk
// so acc1 and phase2 registers are not co-live.
// phase2 roles: every wave owns feat row-group wid; waves 0..4 own E group wid.
__global__ __launch_bounds__(512, 4) void fused_mlp(
    const short* __restrict__ W1f_, const float* __restrict__ B1p_,
    const short* __restrict__ W2af_, const float* __restrict__ fb2_0, const float* __restrict__ fb2_1,
    const short* __restrict__ W2bf_, const float* __restrict__ B2bp_,
    const short* __restrict__ xT, const short* __restrict__ x1T,
    float* __restrict__ feat0, float* __restrict__ feat1,
    short* __restrict__ Eg0, short* __restrict__ Eg1,
    float* __restrict__ pu0, float* __restrict__ pu1)
{
    __shared__ short xs[12 * 2048];   // 48 KB
    __shared__ short hs[8 * 2048];    // 32 KB (256 k-rows x 64 n, B-fragment order)
    const int tid = threadIdx.x;
    const int wid = tid >> 6, lane = tid & 63;   // wid 0..7
    const int l15 = lane & 15, q = lane >> 4;
    const int bx = blockIdx.x, b = blockIdx.y;
    const int sc = bx >= 64;
    const int tile = sc ? bx - 64 : bx;
    const int N = sc ? 1024 : 4096;
    const int n0 = tile * 64;
    const short* XT = sc ? x1T : xT;
    const short* W1f = W1f_ + (size_t)sc * 491520;
    const float* B1p = B1p_ + sc * 1280;
    const short* W2af = W2af_ + (size_t)sc * 65536;
    const short* W2bf = W2bf_ + (size_t)sc * 98304;
    const float* fb2 = sc ? fb2_1 : fb2_0;
    const float* B2bp = B2bp_ + sc * 128;
    float* feat = (sc ? feat1 : feat0) + (long)b * 128 * N;
    short* Eg = (sc ? Eg1 : Eg0) + (long)b * 65 * N;
    float* pu = sc ? pu1 : pu0;
    const int npart = sc ? 16 : 64;

    // stage x tile [64 n x 384 k] into fragment-order LDS (512 threads)
    {
        const int n = tid >> 3;          // 0..63
        const int c0 = (tid & 7) * 6;    // 8 threads cover 48 c-groups
        const short* src = XT + ((long)b * N + n0 + n) * 384 + c0 * 8;
        const int jj = n >> 4, nl = n & 15;
        #pragma unroll
        for (int i = 0; i < 6; i++) {
            int c = c0 + i;
            int kc = c >> 2, qq = c & 3;
            *(short8*)(xs + kc * 2048 + jj * 512 + ((qq << 4) | nl) * 8) =
                *(const short8*)(src + i * 8);
        }
    }
    __syncthreads();

    floatx4 acc2[2][4];   // [0] = feat group wid, [1] = E group wid (wid<5)
    #pragma unroll
    for (int i = 0; i < 2; i++)
        #pragma unroll
        for (int j = 0; j < 4; j++) acc2[i][j] = floatx4{0.f, 0.f, 0.f, 0.f};

    auto phase2 = [&](int pc) {
        if (pc < 2) {
            const short* WA = W2af + (size_t)pc * 32768;
            short8 hb[2][4], wa[2];
            #pragma unroll
            for (int j = 0; j < 4; j++) hb[0][j] = *(short8*)(hs + j * 512 + lane * 8);
            wa[0] = *(const short8*)(WA + wid * 512 + lane * 8);
            #pragma unroll
            for (int kc2 = 0; kc2 < 8; kc2++) {
                short8 bfr[4];
                #pragma unroll
                for (int j = 0; j < 4; j++) bfr[j] = hb[kc2 & 1][j];
                short8 aF = wa[kc2 & 1];
                if (kc2 + 1 < 8) {
                    #pragma unroll
                    for (int j = 0; j < 4; j++)
                        hb[(kc2 + 1) & 1][j] = *(short8*)(hs + (kc2 + 1) * 2048 + j * 512 + lane * 8);
                    wa[(kc2 + 1) & 1] = *(const short8*)(WA + ((kc2 + 1) * 8 + wid) * 512 + lane * 8);
                }
                #pragma unroll
                for (int j = 0; j < 4; j++)
                    acc2[0][j] = __builtin_amdgcn_mfma_f32_16x16x32_bf16(aF, bfr[j], acc2[0][j], 0, 0, 0);
            }
        } else {
            if (wid >= 5) return;   // wave-uniform: E rows only on waves 0..4
            const short* WB = W2bf + (size_t)(pc - 2) * 32768;
            short8 hb[2][4], we[2];
            #pragma unroll
            for (int j = 0; j < 4; j++) hb[0][j] = *(short8*)(hs + j * 512 + lane * 8);
            we[0] = *(const short8*)(WB + wid * 512 + lane * 8);
            #pragma unroll
            for (int kc2 = 0; kc2 < 8; kc2++) {
                short8 bfr[4];
                #pragma unroll
                for (int j = 0; j < 4; j++) bfr[j] = hb[kc2 & 1][j];
                short8 aE = we[kc2 & 1];
                if (kc2 + 1 < 8) {
                    #pragma unroll
                    for (int j = 0; j < 4; j++)
                        hb[(kc2 + 1) & 1][j] = *(short8*)(hs + (kc2 + 1) * 2048 + j * 512 + lane * 8);
                    we[(kc2 + 1) & 1] = *(const short8*)(WB + ((kc2 + 1) * 8 + wid) * 512 + lane * 8);
                }
                #pragma unroll
                for (int j = 0; j < 4; j++)
                    acc2[1][j] = __builtin_amdgcn_mfma_f32_16x16x32_bf16(aE, bfr[j], acc2[1][j], 0, 0, 0);
            }
        }
    };

    for (int c = 0; c < 5; c++) {
        if (c > 0) phase2(c - 1);   // reads hs chunk c-1 (published at end of prev iter)
        // phase1: h rows c*256 + wid*32 .. +31; 2-deep global A prefetch
        floatx4 acc1[2][4];
        #pragma unroll
        for (int i = 0; i < 2; i++)
            #pragma unroll
            for (int j = 0; j < 4; j++) acc1[i][j] = floatx4{0.f, 0.f, 0.f, 0.f};
        const short* Wb = W1f + (long)c * 98304;
        short8 abuf[2][2];
        #pragma unroll
        for (int i = 0; i < 2; i++) {
            abuf[0][i] = *(const short8*)(Wb + (wid * 2 + i) * 512 + lane * 8);
            abuf[1][i] = *(const short8*)(Wb + (16 + wid * 2 + i) * 512 + lane * 8);
        }
        #pragma unroll
        for (int kc = 0; kc < 12; kc++) {
            short8 ac[2], bc[4];
            #pragma unroll
            for (int i = 0; i < 2; i++) ac[i] = abuf[kc & 1][i];
            #pragma unroll
            for (int j = 0; j < 4; j++) bc[j] = *(short8*)(xs + kc * 2048 + j * 512 + lane * 8);
            if (kc + 2 < 12) {
                #pragma unroll
                for (int i = 0; i < 2; i++)
                    abuf[kc & 1][i] = *(const short8*)(Wb + ((kc + 2) * 16 + wid * 2 + i) * 512 + lane * 8);
            }
            #pragma unroll
            for (int i = 0; i < 2; i++)
                #pragma unroll
                for (int j = 0; j < 4; j++)
                    acc1[i][j] = __builtin_amdgcn_mfma_f32_16x16x32_bf16(ac[i], bc[j], acc1[i][j], 0, 0, 0);
        }
        __syncthreads();   // hs readers (phase2 of chunk c-1) done
        // h-chunk -> hs (bias + relu + bf16), phase-2 B-fragment order
        // rows wid*32 + i*16 + q*4 + rr  ->  kc2=wid, qf=i*2+(q>>1), e0=4*(q&1)
        #pragma unroll
        for (int i = 0; i < 2; i++) {
            const int qf = i * 2 + (q >> 1);
            const int e0 = 4 * (q & 1);
            const int mrow = c * 256 + wid * 32 + i * 16 + q * 4;
            float bw[4];
            #pragma unroll
            for (int rr = 0; rr < 4; rr++) bw[rr] = B1p[mrow + rr];
            #pragma unroll
            for (int j = 0; j < 4; j++) {
                short pk[4];
                #pragma unroll
                for (int rr = 0; rr < 4; rr++)
                    pk[rr] = f2bf(fmaxf(acc1[i][j][rr] + bw[rr], 0.f));
                *(unsigned long long*)(hs + wid * 2048 + j * 512 + ((qf << 4) | l15) * 8 + e0) =
                    *(unsigned long long*)pk;
            }
        }
        __syncthreads();   // hs visible
    }
    phase2(4);

    // epilogue: feat (every wave owns rows wid*16 .. +15)
    {
        const int row0 = wid * 16 + q * 4;
        #pragma unroll
        for (int rr = 0; rr < 4; rr++) {
            float bv = fb2[row0 + rr];
            #pragma unroll
            for (int j = 0; j < 4; j++)
                feat[(long)(row0 + rr) * N + n0 + 16 * j + l15] = acc2[0][j][rr] + bv;
        }
    }
    __syncthreads();               // all phase2(4) hs reads done; reuse hs
    float* puld = (float*)hs;
    if (wid < 4) {
        // E rows wid*16 .. +15
        #pragma unroll
        for (int rr = 0; rr < 4; rr++) {
            int row = wid * 16 + q * 4 + rr;
            float bv = B2bp[row];
            float s = 0.f;
            #pragma unroll
            for (int j = 0; j < 4; j++) {
                float e = expf(acc2[1][j][rr] + bv);
                Eg[(long)row * N + n0 + 16 * j + l15] = f2bf(e);
                s += e;
            }
            s += __shfl_xor(s, 1); s += __shfl_xor(s, 2);
            s += __shfl_xor(s, 4); s += __shfl_xor(s, 8);
            if (l15 == 0) puld[row] = s;
        }
    } else if (wid == 4) {
        // dustbin row 64 only
        #pragma unroll
        for (int rr = 0; rr < 4; rr++) {
            int row = 64 + q * 4 + rr;
            bool valid = (row == 64);
            float bv = B2bp[64];
            float s = 0.f;
            #pragma unroll
            for (int j = 0; j < 4; j++) {
                float e = expf(acc2[1][j][rr] + bv);
                if (valid) {
                    Eg[(long)64 * N + n0 + 16 * j + l15] = f2bf(e);
                    s += e;
                }
            }
            s += __shfl_xor(s, 1); s += __shfl_xor(s, 2);
            s += __shfl_xor(s, 4); s += __shfl_xor(s, 8);
            if (valid && l15 == 0) puld[64] = s;
        }
    }
    __syncthreads();
    if (tid < 65)
        pu[((long)b * npart + tile) * 65 + tid] = puld[tid];
}

// ---------------- sk_step (both scales): eu from pin; v-step; next u-partials ----------------
__global__ __launch_bounds__(256) void sk_step(
    const short* __restrict__ Eg0, const short* __restrict__ Eg1,
    const float* __restrict__ pin0, const float* __restrict__ pin1,
    float* __restrict__ pout0, float* __restrict__ pout1, int nin0, int nin1)
{
    __shared__ short Es[65 * 264];
    __shared__ float evs[256];
    __shared__ float eus[65];
    const int t = threadIdx.x;
    const int bx = blockIdx.x, b = blockIdx.y;
    const int sc = bx >= 16;
    const int chunk = sc ? bx - 16 : bx;
    const int N = sc ? 1024 : 4096;
    const float invN = sc ? (1.0f / 1024.0f) : (1.0f / 4096.0f);
    const int n0 = chunk * 256;
    const short* Eb = (sc ? Eg1 : Eg0) + (long)b * 65 * N;
    const float* pin = sc ? pin1 : pin0;
    const int nin = sc ? nin1 : nin0;
    float* pout = sc ? pout1 : pout0;
    const int nout = sc ? 4 : 16;
    if (t < 65) {
        float s = 0.f;
        for (int ch = 0; ch < nin; ch++) s += pin[((long)b * nin + ch) * 65 + t];
        eus[t] = (1.0f / 65.0f) / s;
    }
    for (int it = t; it < 2080; it += 256) {
        int k = it >> 5, n8 = it & 31;
        *(short8*)(Es + k * 264 + n8 * 8) = *(const short8*)(Eb + (long)k * N + n0 + n8 * 8);
    }
    __syncthreads();
    float sv = 0.f;
    #pragma unroll 4
    for (int k = 0; k < 65; k++) sv += bf2f(Es[k * 264 + t]) * eus[k];
    evs[t] = invN / sv;
    __syncthreads();
    const int wid = t >> 6, lane = t & 63;
    for (int k = wid; k < 65; k += 4) {
        const short* er = Es + k * 264 + lane * 4;
        float4 v4 = *(const float4*)&evs[lane * 4];
        float s = bf2f(er[0]) * v4.x + bf2f(er[1]) * v4.y + bf2f(er[2]) * v4.z + bf2f(er[3]) * v4.w;
        #pragma unroll
        for (int off = 32; off >= 1; off >>= 1) s += __shfl_xor(s, off);
        if (lane == 0) pout[((long)b * nout + chunk) * 65 + k] = s;
    }
}

// ---------------- sk_desc (both scales): eu; final v-step; P; desc partials via MFMA ----------------
__global__ __launch_bounds__(256) void sk_desc(
    const short* __restrict__ Eg0, const short* __restrict__ Eg1,
    const float* __restrict__ pin0, const float* __restrict__ pin1,
    const float* __restrict__ feat0, const float* __restrict__ feat1,
    float* __restrict__ part0, float* __restrict__ part1, int nin0, int nin1)
{
    __shared__ short Es[65 * 264];
    __shared__ float eus[65];
    const int t = threadIdx.x;
    const int bx = blockIdx.x, b = blockIdx.y;
    const int sc = bx >= 16;
    const int chunk = sc ? bx - 16 : bx;
    const int N = sc ? 1024 : 4096;
    const float invN = sc ? (1.0f / 1024.0f) : (1.0f / 4096.0f);
    const int nch = sc ? 4 : 16;
    const int n0 = chunk * 256;
    const short* Eb = (sc ? Eg1 : Eg0) + (long)b * 65 * N;
    const float* pin = sc ? pin1 : pin0;
    const int nin = sc ? nin1 : nin0;
    const float* fb = (sc ? feat1 : feat0) + (long)b * 128 * N;
    float* part = sc ? part1 : part0;
    if (t < 65) {
        float s = 0.f;
        for (int ch = 0; ch < nin; ch++) s += pin[((long)b * nin + ch) * 65 + t];
        eus[t] = (1.0f / 65.0f) / s;
    }
    for (int it = t; it < 2080; it += 256) {
        int k = it >> 5, n8 = it & 31;
        *(short8*)(Es + k * 264 + n8 * 8) = *(const short8*)(Eb + (long)k * N + n0 + n8 * 8);
    }
    __syncthreads();
    float sv = 0.f;
    #pragma unroll 4
    for (int k = 0; k < 65; k++) sv += bf2f(Es[k * 264 + t]) * eus[k];
    float evt = invN / sv;
    #pragma unroll 4
    for (int k = 0; k < 64; k++)
        Es[k * 264 + t] = f2bf(bf2f(Es[k * 264 + t]) * eus[k] * evt);
    __syncthreads();
    const int wid = t >> 6, lane = t & 63;
    const int l15 = lane & 15, q = lane >> 4;
    float* pb = part + ((long)b * nch + chunk) * 8256;
    // P row-sum partials (denominator)
    for (int k = wid; k < 64; k += 4) {
        const short* er = Es + k * 264 + lane * 4;
        float s = bf2f(er[0]) + bf2f(er[1]) + bf2f(er[2]) + bf2f(er[3]);
        #pragma unroll
        for (int off = 32; off >= 1; off >>= 1) s += __shfl_xor(s, off);
        if (lane == 0) pb[8192 + k] = s;
    }
    // MFMA einsum: wave wid owns c rows wid*32 .. +31 (2 m-tiles), all 64 k-cols (4 n-tiles)
    floatx4 acc[2][4];
    #pragma unroll
    for (int mt = 0; mt < 2; mt++)
        #pragma unroll
        for (int nt = 0; nt < 4; nt++) acc[mt][nt] = floatx4{0.f, 0.f, 0.f, 0.f};
    #pragma unroll 2
    for (int ks = 0; ks < 8; ks++) {
        short8 ah[2], al[2];
        #pragma unroll
        for (int mt = 0; mt < 2; mt++) {
            const float* fp = fb + (long)(wid * 32 + mt * 16 + l15) * N + n0 + ks * 32 + q * 8;
            float4 v0 = *(const float4*)fp;
            float4 v1 = *(const float4*)(fp + 4);
            float va[8] = {v0.x, v0.y, v0.z, v0.w, v1.x, v1.y, v1.z, v1.w};
            short hh[8], ll[8];
            #pragma unroll
            for (int e = 0; e < 8; e++) {
                short h = f2bf(va[e]);
                hh[e] = h;
                ll[e] = f2bf(va[e] - bf2f(h));
            }
            ah[mt] = *(short8*)hh;
            al[mt] = *(short8*)ll;
        }
        #pragma unroll
        for (int nt = 0; nt < 4; nt++) {
            short8 bfr = *(short8*)(Es + (nt * 16 + l15) * 264 + ks * 32 + q * 8);
            #pragma unroll
            for (int mt = 0; mt < 2; mt++) {
                acc[mt][nt] = __builtin_amdgcn_mfma_f32_16x16x32_bf16(al[mt], bfr, acc[mt][nt], 0, 0, 0);
                acc[mt][nt] = __builtin_amdgcn_mfma_f32_16x16x32_bf16(ah[mt], bfr, acc[mt][nt], 0, 0, 0);
            }
        }
    }
    // C/D layout: col = lane&15 (k-index), row = q*4+rr (c-row within tile)
    #pragma unroll
    for (int mt = 0; mt < 2; mt++)
        #pragma unroll
        for (int nt = 0; nt < 4; nt++)
            #pragma unroll
            for (int rr = 0; rr < 4; rr++)
                pb[(wid * 32 + mt * 16 + q * 4 + rr) * 64 + nt * 16 + l15] = acc[mt][nt][rr];
}

// ---------------- desc reduce (both scales; separate desc buffers) ----------------
__global__ __launch_bounds__(256) void desc_reduce(
    const float* __restrict__ part0, const float* __restrict__ part1,
    float* __restrict__ desc0, float* __restrict__ desc1, int b0)
{
    __shared__ float cred[4][8];
    const int bx = blockIdx.x, b = blockIdx.y;
    const int sc = bx >= 4;
    const int kg = (bx & 3) * 16;
    const int nch = sc ? 4 : 16;
    const float* pb = (sc ? part1 : part0) + (long)b * nch * 8256;
    float* desc = sc ? desc1 : desc0;
    const int t = threadIdx.x;
    const int c = t & 127, kh = t >> 7;
    float a[8], rs[8];
    #pragma unroll
    for (int j = 0; j < 8; j++) { a[j] = 0.f; rs[j] = 0.f; }
    for (int ch = 0; ch < nch; ch++) {
        const float* p = pb + (long)ch * 8256;
        #pragma unroll
        for (int j = 0; j < 8; j++) a[j] += p[c * 64 + kg + kh * 8 + j];
        #pragma unroll
        for (int j = 0; j < 8; j++) rs[j] += p[8192 + kg + kh * 8 + j];
    }
    float sq[8];
    #pragma unroll
    for (int j = 0; j < 8; j++) {
        a[j] *= 1.0f / (rs[j] + 1e-8f);
        sq[j] = a[j] * a[j];
    }
    #pragma unroll
    for (int off = 32; off >= 1; off >>= 1)
        #pragma unroll
        for (int j = 0; j < 8; j++) sq[j] += __shfl_xor(sq[j], off);
    if ((t & 63) == 0) {
        #pragma unroll
        for (int j = 0; j < 8; j++) cred[t >> 6][j] = sq[j];
    }
    __syncthreads();
    float* d = desc + (long)(b0 + b) * 8192;
    #pragma unroll
    for (int j = 0; j < 8; j++) {
        float tot = cred[kh * 2][j] + cred[kh * 2 + 1][j];
        float inv = 1.0f / fmaxf(sqrtf(tot), 1e-12f);
        d[c * 64 + kg + kh * 8 + j] = a[j] * inv;
    }
}

// ---------------- final: g = mean(desc0,desc1); normalize ----------------
__global__ __launch_bounds__(256) void final_kernel(const float* __restrict__ desc0,
                                                    const float* __restrict__ desc1,
                                                    float* __restrict__ out)
{
    __shared__ float red[4];
    const int b = blockIdx.x;
    const float* d0 = desc0 + (long)b * 8192;
    const float* d1 = desc1 + (long)b * 8192;
    float s = 0;
    for (int i = threadIdx.x; i < 8192; i += 256) {
        float t = (d0[i] + d1[i]) * 0.5f; s += t * t;
    }
    const int wave = threadIdx.x >> 6, lane = threadIdx.x & 63;
    #pragma unroll
    for (int off = 32; off >= 1; off >>= 1) s += __shfl_xor(s, off);
    if (lane == 0) red[wave] = s;
    __syncthreads();
    float tot = red[0] + red[1] + red[2] + red[3];
    float inv = 1.0f / fmaxf(sqrtf(tot), 1e-12f);
    for (int i = threadIdx.x; i < 8192; i += 256)
        out[(long)b * 8192 + i] = (d0[i] + d1[i]) * 0.5f * inv;
}

extern "C" void kernel_launch(void* const* d_in, const int* in_sizes, int n_in,
                              void* d_out, int out_size, void* d_ws, size_t ws_size,
                              hipStream_t stream)
{
    (void)in_sizes; (void)n_in; (void)out_size;
    const float* x = (const float*)d_in[0];
    WSet ws2[2];
    const float* fb2p[2];
    for (int s = 0; s < 2; s++) {
        int o = 1 + s * 12;
        ws2[s].fw1 = (const float*)d_in[o + 0];  ws2[s].fb1 = (const float*)d_in[o + 1];
        ws2[s].fw2 = (const float*)d_in[o + 2];  fb2p[s]    = (const float*)d_in[o + 3];
        ws2[s].sw1 = (const float*)d_in[o + 4];  ws2[s].sb1 = (const float*)d_in[o + 5];
        ws2[s].sw2 = (const float*)d_in[o + 6];  ws2[s].sb2 = (const float*)d_in[o + 7];
        ws2[s].dw1 = (const float*)d_in[o + 8];  ws2[s].db1 = (const float*)d_in[o + 9];
        ws2[s].dw2 = (const float*)d_in[o + 10]; ws2[s].db2 = (const float*)d_in[o + 11];
    }

    const size_t fixed = ((size_t)2*491520*2 + 2*65536*2 + 2*98304*2
                        + 2*1280*4 + 2*128*4 + (size_t)2*16*8192*4) + (1 << 16);
    const size_t perb = (size_t)4096*384*2 + (size_t)1024*384*2
                      + (size_t)128*4096*4 + (size_t)128*1024*4
                      + (size_t)65*4096*2 + (size_t)65*1024*2
                      + (size_t)(64+16)*65*4 + (size_t)(16+4)*65*4
                      + (size_t)16*8256*4 + (size_t)4*8256*4 + 8192;
    int CB = 4;
    const int cand[3] = {16, 8, 4};
    for (int ci = 0; ci < 3; ci++)
        if (fixed + (size_t)cand[ci] * perb <= ws_size) { CB = cand[ci]; break; }

    char* p = (char*)d_ws;
    auto alloc = [&](size_t bytes) -> char* {
        char* r = p; p += (bytes + 255) & ~(size_t)255; return r;
    };
    short* W1f   = (short*)alloc((size_t)2 * 491520 * 2);
    short* W2af  = (short*)alloc((size_t)2 * 65536 * 2);
    short* W2bf  = (short*)alloc((size_t)2 * 98304 * 2);
    float* B1p   = (float*)alloc((size_t)2 * 1280 * 4);
    float* B2bp  = (float*)alloc((size_t)2 * 128 * 4);
    float* desc0 = (float*)alloc((size_t)16 * 8192 * 4);
    float* desc1 = (float*)alloc((size_t)16 * 8192 * 4);
    short* xT    = (short*)alloc((size_t)CB * 4096 * 384 * 2);
    short* x1T   = (short*)alloc((size_t)CB * 1024 * 384 * 2);
    float* feat0 = (float*)alloc((size_t)CB * 128 * 4096 * 4);
    float* feat1 = (float*)alloc((size_t)CB * 128 * 1024 * 4);
    short* Eg0   = (short*)alloc((size_t)CB * 65 * 4096 * 2);
    short* Eg1   = (short*)alloc((size_t)CB * 65 * 1024 * 2);
    float* puA0  = (float*)alloc((size_t)CB * 64 * 65 * 4);
    float* puA1  = (float*)alloc((size_t)CB * 16 * 65 * 4);
    float* puB0  = (float*)alloc((size_t)CB * 16 * 65 * 4);
    float* puB1  = (float*)alloc((size_t)CB * 4 * 65 * 4);
    float* part0 = (float*)alloc((size_t)CB * 16 * 8256 * 4);
    float* part1 = (float*)alloc((size_t)CB * 4 * 8256 * 4);

    wprep<<<dim3(2566, 2), 256, 0, stream>>>(ws2[0], ws2[1], W1f, W2af, W2bf, B1p, B2bp);

    for (int b0 = 0; b0 < 16; b0 += CB) {
        xprep<<<dim3(32, 6, CB), 256, 0, stream>>>(x + (size_t)b0 * 384 * 4096, xT, x1T);
        fused_mlp<<<dim3(80, CB), 512, 0, stream>>>(
            W1f, B1p, W2af, fb2p[0], fb2p[1], W2bf, B2bp,
            xT, x1T, feat0, feat1, Eg0, Eg1, puA0, puA1);
        sk_step<<<dim3(20, CB), 256, 0, stream>>>(Eg0, Eg1, puA0, puA1, puB0, puB1, 64, 16);
        sk_step<<<dim3(20, CB), 256, 0, stream>>>(Eg0, Eg1, puB0, puB1, puA0, puA1, 16, 4);
        sk_desc<<<dim3(20, CB), 256, 0, stream>>>(Eg0, Eg1, puA0, puA1,
                                                  feat0, feat1, part0, part1, 16, 4);
        desc_reduce<<<dim3(8, CB), 256, 0, stream>>>(part0, part1, desc0, desc1, b0);
    }
    final_kernel<<<16, 256, 0, stream>>>(desc0, desc1, (float*)d_out);
}